// Round 2
// baseline (99.657 us; speedup 1.0000x reference)
//
#include <hip/hip_runtime.h>
#include <math.h>

#define D 512
#define NB_P 1000   // partial-bag blocks

// ---------------- K1: dot[j] = features[j] . attn_w  (one wave per row) ----
__global__ void k_dot(const float* __restrict__ f, const float* __restrict__ w,
                      float* __restrict__ dot, int n) {
    int wave = threadIdx.x >> 6;            // 4 waves / block
    int lane = threadIdx.x & 63;
    int row  = blockIdx.x * 4 + wave;
    if (row >= n) return;
    const float4* fr = (const float4*)(f + (size_t)row * D);
    const float4* wr = (const float4*)w;
    float4 a0 = fr[lane],      b0 = wr[lane];
    float4 a1 = fr[lane + 64], b1 = wr[lane + 64];
    float s = a0.x*b0.x + a0.y*b0.y + a0.z*b0.z + a0.w*b0.w
            + a1.x*b1.x + a1.y*b1.y + a1.z*b1.z + a1.w*b1.w;
    #pragma unroll
    for (int off = 32; off; off >>= 1) s += __shfl_down(s, off);
    if (lane == 0) dot[row] = s;
}

// ---------------- K2: scores[i] = winmean(dot) + b ; per-block max ----------
__global__ void k_scores(const float* __restrict__ dot, const float* __restrict__ bptr,
                         const int* __restrict__ kptr, float* __restrict__ scores,
                         float* __restrict__ pmax, int n) {
    int i = blockIdx.x * blockDim.x + threadIdx.x;
    int k = *kptr;
    float val = -INFINITY;
    if (i < n) {
        int lo = max(i - k, 0), hi = min(i + k, n - 1);
        float s = 0.f;
        for (int j = lo; j <= hi; ++j) s += dot[j];
        val = s / (float)(hi - lo + 1) + bptr[0];
        scores[i] = val;
    }
    float m = val;
    #pragma unroll
    for (int off = 32; off; off >>= 1) m = fmaxf(m, __shfl_down(m, off));
    __shared__ float sm[4];
    int lane = threadIdx.x & 63, wid = threadIdx.x >> 6;
    if (lane == 0) sm[wid] = m;
    __syncthreads();
    if (threadIdx.x == 0) {
        float mm = fmaxf(fmaxf(sm[0], sm[1]), fmaxf(sm[2], sm[3]));
        pmax[blockIdx.x] = mm;
    }
}

// ---------------- K3: global max of pmax --------------------------------
__global__ void k_gmax(const float* __restrict__ pmax, int nb, float* __restrict__ scal) {
    float m = -INFINITY;
    for (int i = threadIdx.x; i < nb; i += blockDim.x) m = fmaxf(m, pmax[i]);
    #pragma unroll
    for (int off = 32; off; off >>= 1) m = fmaxf(m, __shfl_down(m, off));
    __shared__ float sm[4];
    int lane = threadIdx.x & 63, wid = threadIdx.x >> 6;
    if (lane == 0) sm[wid] = m;
    __syncthreads();
    if (threadIdx.x == 0) scal[0] = fmaxf(fmaxf(sm[0], sm[1]), fmaxf(sm[2], sm[3]));
}

// ---------------- K4: e[i] = exp(scores[i]-gmax) in place; per-block sum ----
__global__ void k_exp(float* __restrict__ scores, const float* __restrict__ scal,
                      float* __restrict__ psum, int n) {
    int i = blockIdx.x * blockDim.x + threadIdx.x;
    float gmax = scal[0];
    float e = 0.f;
    if (i < n) {
        e = expf(scores[i] - gmax);
        scores[i] = e;
    }
    #pragma unroll
    for (int off = 32; off; off >>= 1) e += __shfl_down(e, off);
    __shared__ float sm[4];
    int lane = threadIdx.x & 63, wid = threadIdx.x >> 6;
    if (lane == 0) sm[wid] = e;
    __syncthreads();
    if (threadIdx.x == 0) psum[blockIdx.x] = sm[0] + sm[1] + sm[2] + sm[3];
}

// ---------------- K5: gsum -> inv --------------------------------------
__global__ void k_gsum(const float* __restrict__ psum, int nb, float* __restrict__ scal) {
    float s = 0.f;
    for (int i = threadIdx.x; i < nb; i += blockDim.x) s += psum[i];
    #pragma unroll
    for (int off = 32; off; off >>= 1) s += __shfl_down(s, off);
    __shared__ float sm[4];
    int lane = threadIdx.x & 63, wid = threadIdx.x >> 6;
    if (lane == 0) sm[wid] = s;
    __syncthreads();
    if (threadIdx.x == 0) scal[1] = 1.f / (sm[0] + sm[1] + sm[2] + sm[3]);
}

// ---------------- K6: w[j] = e[j]*inv ; u[j] = inv * sum_{i in win(j)} e[i]/cnt(i)
__global__ void k_wu(const float* __restrict__ e, const float* __restrict__ scal,
                     const int* __restrict__ kptr, float* __restrict__ w_out,
                     float* __restrict__ u, int n) {
    int j = blockIdx.x * blockDim.x + threadIdx.x;
    if (j >= n) return;
    int k = *kptr;
    float inv = scal[1];
    w_out[j] = e[j] * inv;
    int lo = max(j - k, 0), hi = min(j + k, n - 1);
    float s = 0.f;
    for (int i = lo; i <= hi; ++i) {
        int li = max(i - k, 0), hh = min(i + k, n - 1);
        s += e[i] / (float)(hh - li + 1);
    }
    u[j] = s * inv;
}

// ---------------- K7: partial bag per block --------------------------------
__global__ void k_pbag(const float* __restrict__ f, const float* __restrict__ u,
                       float* __restrict__ partial, int n, int chunk) {
    int t = threadIdx.x;                         // 128 threads, float4 each = 512 cols
    int j0 = blockIdx.x * chunk;
    int j1 = min(j0 + chunk, n);
    float4 acc = make_float4(0.f, 0.f, 0.f, 0.f);
    for (int j = j0; j < j1; ++j) {
        float uj = u[j];
        float4 v = ((const float4*)(f + (size_t)j * D))[t];
        acc.x += uj * v.x; acc.y += uj * v.y;
        acc.z += uj * v.z; acc.w += uj * v.w;
    }
    ((float4*)(partial + (size_t)blockIdx.x * D))[t] = acc;
}

// ---------------- K8: reduce partial[NB_P][512] -> bag[512] ------------------
__global__ void k_rbag(const float* __restrict__ partial, float* __restrict__ bag, int nb) {
    int c = blockIdx.x * 16 + (threadIdx.x & 15);   // 32 blocks x 16 cols
    int r = threadIdx.x >> 4;                       // 16 row-groups
    float acc = 0.f;
    for (int b = r; b < nb; b += 16) acc += partial[(size_t)b * D + c];
    __shared__ float sm[256];
    sm[threadIdx.x] = acc;
    __syncthreads();
    if (threadIdx.x < 16) {
        float s = 0.f;
        #pragma unroll
        for (int q = 0; q < 16; ++q) s += sm[q * 16 + threadIdx.x];
        bag[blockIdx.x * 16 + threadIdx.x] = s;
    }
}

extern "C" void kernel_launch(void* const* d_in, const int* in_sizes, int n_in,
                              void* d_out, int out_size, void* d_ws, size_t ws_size,
                              hipStream_t stream) {
    const float* f  = (const float*)d_in[0];
    const float* aw = (const float*)d_in[1];
    const float* ab = (const float*)d_in[2];
    const int*   kp = (const int*)d_in[3];
    int n = in_sizes[0] / D;

    float* bag   = (float*)d_out;        // [512]
    float* w_out = (float*)d_out + D;    // [n]

    float* wsf    = (float*)d_ws;
    int nb2       = (n + 255) / 256;
    float* dot    = wsf;                 // n
    float* scores = wsf + n;             // n (reused as e)
    float* u      = wsf + 2 * (size_t)n; // n
    float* pmax   = wsf + 3 * (size_t)n; // nb2
    float* psum   = pmax + nb2;          // nb2
    float* scal   = psum + nb2;          // 2 (gmax, inv_gsum)
    size_t poff   = ((3 * (size_t)n + 2 * (size_t)nb2 + 2) + 15) & ~(size_t)15;
    float* partial = wsf + poff;         // NB_P * 512

    int chunk = (n + NB_P - 1) / NB_P;

    k_dot   <<<(n + 3) / 4, 256, 0, stream>>>(f, aw, dot, n);
    k_scores<<<nb2, 256, 0, stream>>>(dot, ab, kp, scores, pmax, n);
    k_gmax  <<<1, 256, 0, stream>>>(pmax, nb2, scal);
    k_exp   <<<nb2, 256, 0, stream>>>(scores, scal, psum, n);
    k_gsum  <<<1, 256, 0, stream>>>(psum, nb2, scal);
    k_wu    <<<nb2, 256, 0, stream>>>(scores, scal, kp, w_out, u, n);
    k_pbag  <<<NB_P, 128, 0, stream>>>(f, u, partial, n, chunk);
    k_rbag  <<<32, 256, 0, stream>>>(partial, bag, NB_P);
}